// Round 1
// baseline (208.652 us; speedup 1.0000x reference)
//
#include <hip/hip_runtime.h>
#include <hip/hip_bf16.h>
#include <cstdint>

#define B_ 8
#define S_ 2048
#define NI_ 1024
#define D_ 128
#define M_ (B_ * S_)  // 16384

typedef __attribute__((ext_vector_type(8))) short bf16x8;
typedef __attribute__((ext_vector_type(8))) unsigned short u16x8;
typedef __attribute__((ext_vector_type(4))) float f32x4;

__device__ __forceinline__ unsigned short f2bf(float f) {
    union { float f; uint32_t u; } v; v.f = f;
    uint32_t u = v.u;
    u += 0x7fff + ((u >> 16) & 1);  // RNE
    return (unsigned short)(u >> 16);
}

// ---------------- kernel 1: x fp32 -> bf16 ----------------
__global__ __launch_bounds__(256) void k_cvt_x(const float* __restrict__ x,
                                               unsigned short* __restrict__ xb) {
    int t = blockIdx.x * 256 + threadIdx.x;  // 2,097,152 threads exactly
    long base = (long)t * 8;
    float4 a = *(const float4*)(x + base);
    float4 b = *(const float4*)(x + base + 4);
    u16x8 r;
    r[0] = f2bf(a.x); r[1] = f2bf(a.y); r[2] = f2bf(a.z); r[3] = f2bf(a.w);
    r[4] = f2bf(b.x); r[5] = f2bf(b.y); r[6] = f2bf(b.z); r[7] = f2bf(b.w);
    *(u16x8*)(xb + base) = r;
}

// ---------------- kernel 2: pack Wq/Wk/Wv -> wb[384][1024] bf16, biases -> fp32[384] ----
__global__ __launch_bounds__(256) void k_pack_w(const float* __restrict__ Wq, const float* __restrict__ bq,
                                                const float* __restrict__ Wk, const float* __restrict__ bk,
                                                const float* __restrict__ Wv, const float* __restrict__ bv,
                                                unsigned short* __restrict__ wb, float* __restrict__ bias) {
    int t = blockIdx.x * 256 + threadIdx.x;  // 49,152 threads exactly
    int e = t * 8;
    const float* src; int off;
    if (e < 131072)      { src = Wq; off = e; }
    else if (e < 262144) { src = Wk; off = e - 131072; }
    else                 { src = Wv; off = e - 262144; }
    float4 a = *(const float4*)(src + off);
    float4 b = *(const float4*)(src + off + 4);
    u16x8 r;
    r[0] = f2bf(a.x); r[1] = f2bf(a.y); r[2] = f2bf(a.z); r[3] = f2bf(a.w);
    r[4] = f2bf(b.x); r[5] = f2bf(b.y); r[6] = f2bf(b.z); r[7] = f2bf(b.w);
    *(u16x8*)(wb + e) = r;
    if (t < 384)
        bias[t] = (t < 128) ? bq[t] : (t < 256) ? bk[t - 128] : bv[t - 256];
}

// ---------------- kernel 3: QKV GEMM (m97-style 128x128 tile, BK=32) ----------------
// C[m,n] = sum_k xb[m,k]*wb[n,k] + bias[n]; n0-block selects q / k / vT output.
__global__ __launch_bounds__(256) void k_qkv(const unsigned short* __restrict__ xb,
                                             const unsigned short* __restrict__ wb,
                                             const float* __restrict__ bias,
                                             unsigned short* __restrict__ q,
                                             unsigned short* __restrict__ kout,
                                             unsigned short* __restrict__ vT) {
    __shared__ __align__(16) unsigned short As[128 * 32];
    __shared__ __align__(16) unsigned short Bs[128 * 32];
    const int tid = threadIdx.x;
    const int m0 = blockIdx.x * 128;
    const int n0 = blockIdx.y * 128;
    const int l = tid & 63, w = tid >> 6;
    const int wr = w >> 1, wc = w & 1;
    const int lr = l & 15, lg = l >> 4;
    const int sr = tid >> 2;          // staging row 0..63
    const int sc = (tid & 3) * 8;     // staging col

    f32x4 acc[4][4] = {};

    for (int k0 = 0; k0 < NI_; k0 += 32) {
        *(u16x8*)(As + sr * 32 + sc)        = *(const u16x8*)(xb + (long)(m0 + sr) * NI_ + k0 + sc);
        *(u16x8*)(As + (sr + 64) * 32 + sc) = *(const u16x8*)(xb + (long)(m0 + sr + 64) * NI_ + k0 + sc);
        *(u16x8*)(Bs + sr * 32 + sc)        = *(const u16x8*)(wb + (long)(n0 + sr) * NI_ + k0 + sc);
        *(u16x8*)(Bs + (sr + 64) * 32 + sc) = *(const u16x8*)(wb + (long)(n0 + sr + 64) * NI_ + k0 + sc);
        __syncthreads();
        bf16x8 a[4], b[4];
#pragma unroll
        for (int i = 0; i < 4; i++)
            a[i] = *(const bf16x8*)(As + (wr * 64 + i * 16 + lr) * 32 + lg * 8);
#pragma unroll
        for (int j = 0; j < 4; j++)
            b[j] = *(const bf16x8*)(Bs + (wc * 64 + j * 16 + lr) * 32 + lg * 8);
#pragma unroll
        for (int i = 0; i < 4; i++)
#pragma unroll
            for (int j = 0; j < 4; j++)
                acc[i][j] = __builtin_amdgcn_mfma_f32_16x16x32_bf16(a[i], b[j], acc[i][j], 0, 0, 0);
        __syncthreads();
    }

#pragma unroll
    for (int i = 0; i < 4; i++)
#pragma unroll
        for (int j = 0; j < 4; j++)
#pragma unroll
            for (int r = 0; r < 4; r++) {
                int row = m0 + wr * 64 + i * 16 + lg * 4 + r;  // C/D: row=(l>>4)*4+reg
                int n = n0 + wc * 64 + j * 16 + lr;            // C/D: col=l&15
                float val = acc[i][j][r] + bias[n];
                unsigned short bv16 = f2bf(val);
                if (n0 == 0)        q[(long)row * 128 + n] = bv16;
                else if (n0 == 128) kout[(long)row * 128 + (n - 128)] = bv16;
                else {
                    int bb = row >> 11, s = row & 2047, d = n - 256;
                    vT[((long)bb * 128 + d) * (long)S_ + s] = bv16;  // transposed V
                }
            }
}

// ---------------- kernel 4: flash attention ----------------
// 4 waves/block, each wave owns 16 q-rows; KV tiles of 32; online softmax.
__global__ __launch_bounds__(256) void k_attn(const unsigned short* __restrict__ q,
                                              const unsigned short* __restrict__ kk,
                                              const unsigned short* __restrict__ vT,
                                              float* __restrict__ out) {
    __shared__ __align__(16) unsigned short Plds[4 * 16 * 32];  // 1KB per wave
    const int tid = threadIdx.x, l = tid & 63, w = tid >> 6;
    const int b = blockIdx.y;
    const int q0 = blockIdx.x * 64 + w * 16;
    const int lr = l & 15, lg = l >> 4;
    const unsigned short* qB = q  + (long)b * S_ * 128;
    const unsigned short* kB = kk + (long)b * S_ * 128;
    const unsigned short* vB = vT + (long)b * 128 * S_;
    unsigned short* Pw = Plds + w * 512;

    bf16x8 qf[4];
#pragma unroll
    for (int kc = 0; kc < 4; kc++)
        qf[kc] = *(const bf16x8*)(qB + (long)(q0 + lr) * 128 + kc * 32 + lg * 8);

    float mr[4], sr[4];
#pragma unroll
    for (int r = 0; r < 4; r++) { mr[r] = -1e30f; sr[r] = 0.f; }
    f32x4 o[8] = {};

    for (int kv = 0; kv < S_; kv += 32) {
        f32x4 sa[2] = {};
#pragma unroll
        for (int j = 0; j < 2; j++)
#pragma unroll
            for (int kc = 0; kc < 4; kc++) {
                bf16x8 kf = *(const bf16x8*)(kB + (long)(kv + j * 16 + lr) * 128 + kc * 32 + lg * 8);
                sa[j] = __builtin_amdgcn_mfma_f32_16x16x32_bf16(qf[kc], kf, sa[j], 0, 0, 0);
            }
        // online softmax: lane holds rows lg*4+r, key j*16+lr
        float p[2][4];
#pragma unroll
        for (int r = 0; r < 4; r++) {
            float pm = fmaxf(sa[0][r], sa[1][r]);
            pm = fmaxf(pm, __shfl_xor(pm, 1));
            pm = fmaxf(pm, __shfl_xor(pm, 2));
            pm = fmaxf(pm, __shfl_xor(pm, 4));
            pm = fmaxf(pm, __shfl_xor(pm, 8));
            float Mx = fmaxf(mr[r], pm);
            float scale = __expf(mr[r] - Mx);
            float p0 = __expf(sa[0][r] - Mx);
            float p1 = __expf(sa[1][r] - Mx);
            float ps = p0 + p1;
            ps += __shfl_xor(ps, 1);
            ps += __shfl_xor(ps, 2);
            ps += __shfl_xor(ps, 4);
            ps += __shfl_xor(ps, 8);
            sr[r] = sr[r] * scale + ps;
            mr[r] = Mx;
            p[0][r] = p0; p[1][r] = p1;
#pragma unroll
            for (int c = 0; c < 8; c++) o[c][r] *= scale;
        }
        // P: C-layout -> LDS -> A-layout (wave-private region, in-order DS ops)
#pragma unroll
        for (int j = 0; j < 2; j++)
#pragma unroll
            for (int r = 0; r < 4; r++)
                Pw[(lg * 4 + r) * 32 + j * 16 + lr] = f2bf(p[j][r]);
        bf16x8 pa = *(const bf16x8*)(Pw + lr * 32 + lg * 8);
#pragma unroll
        for (int c = 0; c < 8; c++) {
            bf16x8 vf = *(const bf16x8*)(vB + (long)(c * 16 + lr) * S_ + kv + lg * 8);
            o[c] = __builtin_amdgcn_mfma_f32_16x16x32_bf16(pa, vf, o[c], 0, 0, 0);
        }
    }
#pragma unroll
    for (int c = 0; c < 8; c++)
#pragma unroll
        for (int r = 0; r < 4; r++) {
            int row = q0 + lg * 4 + r;
            out[((long)(b * S_ + row)) * 128 + c * 16 + lr] = o[c][r] / sr[r];
        }
}

extern "C" void kernel_launch(void* const* d_in, const int* in_sizes, int n_in,
                              void* d_out, int out_size, void* d_ws, size_t ws_size,
                              hipStream_t stream) {
    const float* x  = (const float*)d_in[0];
    const float* Wq = (const float*)d_in[1];
    const float* bq = (const float*)d_in[2];
    const float* Wk = (const float*)d_in[3];
    const float* bk = (const float*)d_in[4];
    const float* Wv = (const float*)d_in[5];
    const float* bv = (const float*)d_in[6];
    float* out = (float*)d_out;

    char* ws = (char*)d_ws;
    // workspace layout (all 16B-aligned):
    unsigned short* xb   = (unsigned short*)(ws);                    // 33,554,432 B
    unsigned short* wb   = (unsigned short*)(ws + 33554432);         //    786,432 B
    float*          bias = (float*)(ws + 33554432 + 786432);         //      1,536 B (pad->4096)
    unsigned short* qb   = (unsigned short*)(ws + 34344960);         //  4,194,304 B
    unsigned short* kb   = (unsigned short*)(ws + 38539264);         //  4,194,304 B
    unsigned short* vT   = (unsigned short*)(ws + 42733568);         //  4,194,304 B  (end ~44.8MB)

    k_cvt_x<<<8192, 256, 0, stream>>>(x, xb);
    k_pack_w<<<192, 256, 0, stream>>>(Wq, bq, Wk, bk, Wv, bv, wb, bias);
    k_qkv<<<dim3(128, 3), 256, 0, stream>>>(xb, wb, bias, qb, kb, vT);
    k_attn<<<dim3(32, 8), 256, 0, stream>>>(qb, kb, vT, out);
}

// Round 2
// 175.554 us; speedup vs baseline: 1.1885x; 1.1885x over previous
//
#include <hip/hip_runtime.h>
#include <hip/hip_bf16.h>
#include <cstdint>

#define B_ 8
#define S_ 2048
#define NI_ 1024
#define D_ 128
#define M_ (B_ * S_)  // 16384

typedef __attribute__((ext_vector_type(8))) short bf16x8;
typedef __attribute__((ext_vector_type(8))) unsigned short u16x8;
typedef __attribute__((ext_vector_type(4))) float f32x4;

__device__ __forceinline__ unsigned short f2bf(float f) {
    union { float f; uint32_t u; } v; v.f = f;
    uint32_t u = v.u;
    u += 0x7fff + ((u >> 16) & 1);  // RNE
    return (unsigned short)(u >> 16);
}

// ---------------- kernel 1: x fp32 -> bf16 ----------------
__global__ __launch_bounds__(256) void k_cvt_x(const float* __restrict__ x,
                                               unsigned short* __restrict__ xb) {
    int t = blockIdx.x * 256 + threadIdx.x;  // 2,097,152 threads exactly
    long base = (long)t * 8;
    float4 a = *(const float4*)(x + base);
    float4 b = *(const float4*)(x + base + 4);
    u16x8 r;
    r[0] = f2bf(a.x); r[1] = f2bf(a.y); r[2] = f2bf(a.z); r[3] = f2bf(a.w);
    r[4] = f2bf(b.x); r[5] = f2bf(b.y); r[6] = f2bf(b.z); r[7] = f2bf(b.w);
    *(u16x8*)(xb + base) = r;
}

// ---------------- kernel 2: pack Wq/Wk/Wv -> wb[384][1024] bf16, biases -> fp32[384] ----
__global__ __launch_bounds__(256) void k_pack_w(const float* __restrict__ Wq, const float* __restrict__ bq,
                                                const float* __restrict__ Wk, const float* __restrict__ bk,
                                                const float* __restrict__ Wv, const float* __restrict__ bv,
                                                unsigned short* __restrict__ wb, float* __restrict__ bias) {
    int t = blockIdx.x * 256 + threadIdx.x;  // 49,152 threads exactly
    int e = t * 8;
    const float* src; int off;
    if (e < 131072)      { src = Wq; off = e; }
    else if (e < 262144) { src = Wk; off = e - 131072; }
    else                 { src = Wv; off = e - 262144; }
    float4 a = *(const float4*)(src + off);
    float4 b = *(const float4*)(src + off + 4);
    u16x8 r;
    r[0] = f2bf(a.x); r[1] = f2bf(a.y); r[2] = f2bf(a.z); r[3] = f2bf(a.w);
    r[4] = f2bf(b.x); r[5] = f2bf(b.y); r[6] = f2bf(b.z); r[7] = f2bf(b.w);
    *(u16x8*)(wb + e) = r;
    if (t < 384)
        bias[t] = (t < 128) ? bq[t] : (t < 256) ? bk[t - 128] : bv[t - 256];
}

// ---------------- kernel 3: QKV GEMM (m97-style 128x128 tile, BK=32) ----------------
__global__ __launch_bounds__(256) void k_qkv(const unsigned short* __restrict__ xb,
                                             const unsigned short* __restrict__ wb,
                                             const float* __restrict__ bias,
                                             unsigned short* __restrict__ q,
                                             unsigned short* __restrict__ kout,
                                             unsigned short* __restrict__ vT) {
    __shared__ __align__(16) unsigned short As[128 * 32];
    __shared__ __align__(16) unsigned short Bs[128 * 32];
    const int tid = threadIdx.x;
    const int m0 = blockIdx.x * 128;
    const int n0 = blockIdx.y * 128;
    const int l = tid & 63, w = tid >> 6;
    const int wr = w >> 1, wc = w & 1;
    const int lr = l & 15, lg = l >> 4;
    const int sr = tid >> 2;
    const int sc = (tid & 3) * 8;

    f32x4 acc[4][4] = {};

    for (int k0 = 0; k0 < NI_; k0 += 32) {
        *(u16x8*)(As + sr * 32 + sc)        = *(const u16x8*)(xb + (long)(m0 + sr) * NI_ + k0 + sc);
        *(u16x8*)(As + (sr + 64) * 32 + sc) = *(const u16x8*)(xb + (long)(m0 + sr + 64) * NI_ + k0 + sc);
        *(u16x8*)(Bs + sr * 32 + sc)        = *(const u16x8*)(wb + (long)(n0 + sr) * NI_ + k0 + sc);
        *(u16x8*)(Bs + (sr + 64) * 32 + sc) = *(const u16x8*)(wb + (long)(n0 + sr + 64) * NI_ + k0 + sc);
        __syncthreads();
        bf16x8 a[4], b[4];
#pragma unroll
        for (int i = 0; i < 4; i++)
            a[i] = *(const bf16x8*)(As + (wr * 64 + i * 16 + lr) * 32 + lg * 8);
#pragma unroll
        for (int j = 0; j < 4; j++)
            b[j] = *(const bf16x8*)(Bs + (wc * 64 + j * 16 + lr) * 32 + lg * 8);
#pragma unroll
        for (int i = 0; i < 4; i++)
#pragma unroll
            for (int j = 0; j < 4; j++)
                acc[i][j] = __builtin_amdgcn_mfma_f32_16x16x32_bf16(a[i], b[j], acc[i][j], 0, 0, 0);
        __syncthreads();
    }

#pragma unroll
    for (int i = 0; i < 4; i++)
#pragma unroll
        for (int j = 0; j < 4; j++)
#pragma unroll
            for (int r = 0; r < 4; r++) {
                int row = m0 + wr * 64 + i * 16 + lg * 4 + r;
                int n = n0 + wc * 64 + j * 16 + lr;
                float val = acc[i][j][r] + bias[n];
                unsigned short bv16 = f2bf(val);
                if (n0 == 0)        q[(long)row * 128 + n] = bv16;
                else if (n0 == 128) kout[(long)row * 128 + (n - 128)] = bv16;
                else {
                    int bb = row >> 11, s = row & 2047, d = n - 256;
                    vT[((long)bb * 128 + d) * (long)S_ + s] = bv16;
                }
            }
}

// ---------------- kernel 4: flash attention, intra-block KV split ----------------
// 16 waves/block = 4 row-groups x 4 KV-splits. Each wave: 16 q-rows, 512 KV, tiles of 64.
// Online softmax per wave; deterministic LDS combine across the 4 splits.
__global__ __launch_bounds__(1024) void k_attn(const unsigned short* __restrict__ q,
                                               const unsigned short* __restrict__ kk,
                                               const unsigned short* __restrict__ vT,
                                               float* __restrict__ out) {
    __shared__ __align__(16) unsigned short Plds[16 * 16 * 64];  // 32KB: per-wave 16x64 P, XOR-swizzled
    __shared__ __align__(16) float obuf[4][16][132];             // 33.8KB combine accumulator (+4 pad)
    __shared__ float Mlds[16][16];                               // [wave][row]
    __shared__ float Llds[16][16];
    const int tid = threadIdx.x, l = tid & 63, w = tid >> 6;
    const int rw = w & 3, kw = w >> 2;
    const int b = blockIdx.y;
    const int q0 = blockIdx.x * 64 + rw * 16;
    const int lr = l & 15, lg = l >> 4;
    const unsigned short* qB = q  + (long)b * S_ * 128;
    const unsigned short* kB = kk + (long)b * S_ * 128;
    const unsigned short* vB = vT + (long)b * 128 * S_;
    char* Pw = (char*)Plds + w * 2048;

    bf16x8 qf[4];
#pragma unroll
    for (int kc = 0; kc < 4; kc++)
        qf[kc] = *(const bf16x8*)(qB + (long)(q0 + lr) * 128 + kc * 32 + lg * 8);

    float mr[4], sr[4];
#pragma unroll
    for (int r = 0; r < 4; r++) { mr[r] = -1e30f; sr[r] = 0.f; }
    f32x4 o[8] = {};

    const int kv0 = kw * 512;
    for (int kv = kv0; kv < kv0 + 512; kv += 64) {
        f32x4 sa[4] = {};
#pragma unroll
        for (int j = 0; j < 4; j++)
#pragma unroll
            for (int kc = 0; kc < 4; kc++) {
                bf16x8 kf = *(const bf16x8*)(kB + (long)(kv + j * 16 + lr) * 128 + kc * 32 + lg * 8);
                sa[j] = __builtin_amdgcn_mfma_f32_16x16x32_bf16(qf[kc], kf, sa[j], 0, 0, 0);
            }
#pragma unroll
        for (int r = 0; r < 4; r++) {
            float pm = fmaxf(fmaxf(sa[0][r], sa[1][r]), fmaxf(sa[2][r], sa[3][r]));
            pm = fmaxf(pm, __shfl_xor(pm, 1));
            pm = fmaxf(pm, __shfl_xor(pm, 2));
            pm = fmaxf(pm, __shfl_xor(pm, 4));
            pm = fmaxf(pm, __shfl_xor(pm, 8));
            float Mx = fmaxf(mr[r], pm);
            float scale = __expf(mr[r] - Mx);
            int row = lg * 4 + r;
            float ps = 0.f;
#pragma unroll
            for (int j = 0; j < 4; j++) {
                float pj = __expf(sa[j][r] - Mx);
                ps += pj;
                int bo = (row * 128 + (j * 16 + lr) * 2) ^ ((row & 7) << 4);
                *(unsigned short*)(Pw + bo) = f2bf(pj);
            }
            ps += __shfl_xor(ps, 1);
            ps += __shfl_xor(ps, 2);
            ps += __shfl_xor(ps, 4);
            ps += __shfl_xor(ps, 8);
            sr[r] = sr[r] * scale + ps;
            mr[r] = Mx;
#pragma unroll
            for (int c = 0; c < 8; c++) o[c][r] *= scale;
        }
        // P reads in MFMA A-layout, same swizzle
        int bo0 = (lr * 128 + lg * 16) ^ ((lr & 7) << 4);
        int bo1 = (lr * 128 + 64 + lg * 16) ^ ((lr & 7) << 4);
        bf16x8 pa0 = *(const bf16x8*)(Pw + bo0);
        bf16x8 pa1 = *(const bf16x8*)(Pw + bo1);
#pragma unroll
        for (int c = 0; c < 8; c++) {
            bf16x8 vf0 = *(const bf16x8*)(vB + (long)(c * 16 + lr) * S_ + kv + lg * 8);
            o[c] = __builtin_amdgcn_mfma_f32_16x16x32_bf16(pa0, vf0, o[c], 0, 0, 0);
            bf16x8 vf1 = *(const bf16x8*)(vB + (long)(c * 16 + lr) * S_ + kv + 32 + lg * 8);
            o[c] = __builtin_amdgcn_mfma_f32_16x16x32_bf16(pa1, vf1, o[c], 0, 0, 0);
        }
    }

    // ---- combine the 4 KV-splits (deterministic) ----
    if (lr == 0) {
#pragma unroll
        for (int r = 0; r < 4; r++) {
            Mlds[w][lg * 4 + r] = mr[r];
            Llds[w][lg * 4 + r] = sr[r];
        }
    }
    __syncthreads();
    float Lg[4], myw[4];
#pragma unroll
    for (int r = 0; r < 4; r++) {
        int row = lg * 4 + r;
        float m0v = Mlds[rw][row],      m1v = Mlds[4 + rw][row];
        float m2v = Mlds[8 + rw][row],  m3v = Mlds[12 + rw][row];
        float M = fmaxf(fmaxf(m0v, m1v), fmaxf(m2v, m3v));
        Lg[r] = __expf(m0v - M) * Llds[rw][row]
              + __expf(m1v - M) * Llds[4 + rw][row]
              + __expf(m2v - M) * Llds[8 + rw][row]
              + __expf(m3v - M) * Llds[12 + rw][row];
        myw[r] = __expf(mr[r] - M);
    }
    for (int t = 0; t < 4; t++) {
        if (kw == t) {
#pragma unroll
            for (int c = 0; c < 8; c++)
#pragma unroll
                for (int r = 0; r < 4; r++) {
                    int row = lg * 4 + r, col = c * 16 + lr;
                    float v = o[c][r] * myw[r];
                    if (t > 0) v += obuf[rw][row][col];
                    if (t == 3)
                        out[((long)(b * S_ + q0 + row)) * 128 + col] = v / Lg[r];
                    else
                        obuf[rw][row][col] = v;
                }
        }
        __syncthreads();
    }
}

extern "C" void kernel_launch(void* const* d_in, const int* in_sizes, int n_in,
                              void* d_out, int out_size, void* d_ws, size_t ws_size,
                              hipStream_t stream) {
    const float* x  = (const float*)d_in[0];
    const float* Wq = (const float*)d_in[1];
    const float* bq = (const float*)d_in[2];
    const float* Wk = (const float*)d_in[3];
    const float* bk = (const float*)d_in[4];
    const float* Wv = (const float*)d_in[5];
    const float* bv = (const float*)d_in[6];
    float* out = (float*)d_out;

    char* ws = (char*)d_ws;
    unsigned short* xb   = (unsigned short*)(ws);
    unsigned short* wb   = (unsigned short*)(ws + 33554432);
    float*          bias = (float*)(ws + 33554432 + 786432);
    unsigned short* qb   = (unsigned short*)(ws + 34344960);
    unsigned short* kb   = (unsigned short*)(ws + 38539264);
    unsigned short* vT   = (unsigned short*)(ws + 42733568);

    k_cvt_x<<<8192, 256, 0, stream>>>(x, xb);
    k_pack_w<<<192, 256, 0, stream>>>(Wq, bq, Wk, bk, Wv, bv, wb, bias);
    k_qkv<<<dim3(128, 3), 256, 0, stream>>>(xb, wb, bias, qb, kb, vT);
    k_attn<<<dim3(32, 8), 1024, 0, stream>>>(qb, kb, vT, out);
}